// Round 5
// baseline (282.890 us; speedup 1.0000x reference)
//
#include <hip/hip_runtime.h>
#include <stdint.h>

typedef unsigned short u16;
typedef __attribute__((ext_vector_type(8))) short short8;   // 8 bf16 = 4 VGPRs
typedef __attribute__((ext_vector_type(4))) float f32x4;

#define LOG2E 1.44269504088896340736f
#define CS (0.03125f * LOG2E)   // softmax scale 1/sqrt(E)=1/32, folded into exp2 domain
// Problem dims
#define BB 4
#define NN 2048
#define EE 1024
#define HH 16
#define DD 64
#define MM 8192   // B*N
#define C3 3072   // 3*E

#if __has_builtin(__builtin_amdgcn_exp2f)
#define EXP2(x) __builtin_amdgcn_exp2f(x)
#else
#define EXP2(x) exp2f(x)
#endif

__device__ __forceinline__ u16 f2bf(float f) {
  union { float f; unsigned u; } v; v.f = f;
  unsigned r = v.u + 0x7fffu + ((v.u >> 16) & 1u);
  return (u16)(r >> 16);
}

// pack two floats to a bf16 pair; gfx950 has a HW packed convert
#if __has_builtin(__builtin_amdgcn_cvt_pk_bf16_f32)
typedef __attribute__((ext_vector_type(2))) __bf16 bf16x2;
__device__ __forceinline__ unsigned pk2(float a, float b) {
  union { bf16x2 v; unsigned u; } c;
  c.v = __builtin_amdgcn_cvt_pk_bf16_f32(a, b);
  return c.u;
}
#else
__device__ __forceinline__ unsigned pk2(float a, float b) {
  union { float f; unsigned u; } x, y; x.f = a; y.f = b;
  return ((x.u + 0x8000u) >> 16) | ((y.u + 0x8000u) & 0xffff0000u);
}
#endif

__device__ __forceinline__ void async16(const void* g, void* l) {
  __builtin_amdgcn_global_load_lds((const __attribute__((address_space(1))) void*)g,
                                   (__attribute__((address_space(3))) void*)l,
                                   16, 0, 0);
}

// in-tile V key permutation (matches in-register P fragment assembly):
// stored slot s from true key t (6 bits): s = (t5, t3, t2, t4, t1, t0)
__device__ __forceinline__ int vperm(int t) {
  return (t & 0x23) | ((t & 0x0C) << 1) | ((t & 16) >> 2);
}

// ---------------- fused prep kernel ----------------
// blocks [0,8192): cast x fp32->bf16
// blocks [8192,11264): transpose+cast+permute Wqkv -> WqkvT[cp][k]
// blocks [11264,12288): transpose+cast Wproj -> WprojT[c][k]
__global__ __launch_bounds__(256) void prep_kernel(const float* __restrict__ x, u16* __restrict__ xb,
                                                   const float* __restrict__ Wqkv, u16* __restrict__ WqkvT,
                                                   const float* __restrict__ Wproj, u16* __restrict__ WprojT) {
  __shared__ float tile[32][33];
  const int bid = blockIdx.x;
  if (bid < 8192) {
    int i = (bid * 256 + threadIdx.x) * 4;
    float4 v = *(const float4*)(x + i);
    ushort4 o; o.x = f2bf(v.x); o.y = f2bf(v.y); o.z = f2bf(v.z); o.w = f2bf(v.w);
    *(ushort4*)(xb + i) = o;
    return;
  }
  const int permute = bid < 11264 ? 1 : 0;
  const float* W = permute ? Wqkv : Wproj;
  u16* Wt = permute ? WqkvT : WprojT;
  const int ncols = permute ? C3 : EE;
  const int t = permute ? bid - 8192 : bid - 11264;
  const int nbx = permute ? 96 : 32;
  const int c0 = (t % nbx) * 32, k0 = (t / nbx) * 32;
  const int tx = threadIdx.x & 31, ty = threadIdx.x >> 5;  // ty 0..7
#pragma unroll
  for (int r = 0; r < 32; r += 8)
    tile[ty + r][tx] = W[(size_t)(k0 + ty + r) * ncols + c0 + tx];
  __syncthreads();
#pragma unroll
  for (int r = 0; r < 32; r += 8) {
    int c = c0 + ty + r;
    int cp = c;
    if (permute) {
      int tt = c % 3, hh = c / 192, d = (c / 3) % 64;
      cp = tt * 1024 + hh * 64 + d;
    }
    Wt[(size_t)cp * EE + k0 + tx] = f2bf(tile[tx][ty + r]);
  }
}

// ---------------- GEMM core (m97-style, A[M,K] @ Bt[N,K]) ----------------

template <int KDIM>
__device__ __forceinline__ void gemm_core(const u16* __restrict__ A, const u16* __restrict__ Bt,
                                          int m0, int n0, u16* As, u16* Bs, f32x4 acc[4][4]) {
  const int tid = threadIdx.x;
  const int lane = tid & 63, wave = tid >> 6;
  const int q = lane >> 4, r16 = lane & 15;
  const int wrow = (wave >> 1) * 64, wcol = (wave & 1) * 64;
#pragma unroll
  for (int i = 0; i < 4; i++)
#pragma unroll
    for (int j = 0; j < 4; j++) acc[i][j] = (f32x4){0.f, 0.f, 0.f, 0.f};

  for (int k0 = 0; k0 < KDIM; k0 += 32) {
#pragma unroll
    for (int i = 0; i < 2; i++) {
      int chunk = i * 256 + tid;  // 16B chunks; lane-consecutive => LDS-contiguous
      async16(A + (size_t)(m0 + (chunk >> 2)) * KDIM + k0 + (chunk & 3) * 8, &As[chunk * 8]);
      async16(Bt + (size_t)(n0 + (chunk >> 2)) * KDIM + k0 + (chunk & 3) * 8, &Bs[chunk * 8]);
    }
    __syncthreads();
    short8 af[4], bf[4];
#pragma unroll
    for (int i = 0; i < 4; i++)
      af[i] = *(const short8*)&As[(wrow + i * 16 + r16) * 32 + q * 8];
#pragma unroll
    for (int i = 0; i < 4; i++)
      bf[i] = *(const short8*)&Bs[(wcol + i * 16 + r16) * 32 + q * 8];
#pragma unroll
    for (int i = 0; i < 4; i++)
#pragma unroll
      for (int j = 0; j < 4; j++)
        acc[i][j] = __builtin_amdgcn_mfma_f32_16x16x32_bf16(af[i], bf[j], acc[i][j], 0, 0, 0);
    __syncthreads();
  }
}

// QKV GEMM: X[8192,1024] @ WqkvT -> Q(pre-scaled by CS),K to [bh][n][d], V to [bh][d][vperm(n)]
__global__ __launch_bounds__(256) void gemm_qkv(const u16* __restrict__ Xb, const u16* __restrict__ Wt,
                                                const float* __restrict__ bqkv, u16* __restrict__ Qb,
                                                u16* __restrict__ Kb, u16* __restrict__ Vt) {
  __shared__ __align__(16) u16 As[128 * 32];
  __shared__ __align__(16) u16 Bs[128 * 32];
  f32x4 acc[4][4];
  const int m0 = blockIdx.y * 128, n0 = blockIdx.x * 128;
  gemm_core<EE>(Xb, Wt, m0, n0, As, Bs, acc);
  const int tid = threadIdx.x, lane = tid & 63, wave = tid >> 6;
  const int q = lane >> 4, r16 = lane & 15;
  const int wrow = (wave >> 1) * 64, wcol = (wave & 1) * 64;
  // each 128-col block lies entirely in one t-region (Q, K, or V)
  const int t = (n0 + wcol) >> 10;
  const int b = (m0 + wrow) >> 11;          // wave-uniform batch
#pragma unroll
  for (int ci = 0; ci < 4; ci++) {
    const int cp = n0 + wcol + ci * 16 + r16;  // permuted col: t*1024 + h*64 + d
    const int hh = (cp >> 6) & 15, d = cp & 63;
    const float bias = bqkv[hh * 192 + d * 3 + t];  // bias permute folded in
    if (t == 0) {
#pragma unroll
      for (int ri = 0; ri < 4; ri++)
#pragma unroll
        for (int r = 0; r < 4; r++) {
          const int m = m0 + wrow + ri * 16 + q * 4 + r;
          Qb[((size_t)(b * 16 + hh) * 2048 + (m & 2047)) * 64 + d] = f2bf((acc[ri][ci][r] + bias) * CS);
        }
    } else if (t == 1) {
#pragma unroll
      for (int ri = 0; ri < 4; ri++)
#pragma unroll
        for (int r = 0; r < 4; r++) {
          const int m = m0 + wrow + ri * 16 + q * 4 + r;
          Kb[((size_t)(b * 16 + hh) * 2048 + (m & 2047)) * 64 + d] = f2bf(acc[ri][ci][r] + bias);
        }
    } else {
      // V: C rows (quad*4+reg) are n-consecutive; store 8B at the in-tile permuted slot
#pragma unroll
      for (int ri = 0; ri < 4; ri++) {
        const int nb = (m0 + wrow + ri * 16 + q * 4) & 2047;
        const int ns = (nb & ~63) + vperm(nb & 63);  // 4-aligned -> 4-contiguous preserved
        ushort4 w;
        w.x = f2bf(acc[ri][ci][0] + bias);
        w.y = f2bf(acc[ri][ci][1] + bias);
        w.z = f2bf(acc[ri][ci][2] + bias);
        w.w = f2bf(acc[ri][ci][3] + bias);
        *(ushort4*)&Vt[((size_t)(b * 16 + hh) * 64 + d) * 2048 + ns] = w;
      }
    }
  }
}

// Proj GEMM: O[8192,1024] @ WprojT + bproj -> fp32 out
__global__ __launch_bounds__(256) void gemm_proj(const u16* __restrict__ Ob, const u16* __restrict__ Wt,
                                                 const float* __restrict__ bp, float* __restrict__ out) {
  __shared__ __align__(16) u16 As[128 * 32];
  __shared__ __align__(16) u16 Bs[128 * 32];
  f32x4 acc[4][4];
  const int m0 = blockIdx.y * 128, n0 = blockIdx.x * 128;
  gemm_core<EE>(Ob, Wt, m0, n0, As, Bs, acc);
  const int tid = threadIdx.x, lane = tid & 63, wave = tid >> 6;
  const int q = lane >> 4, r16 = lane & 15;
  const int wrow = (wave >> 1) * 64, wcol = (wave & 1) * 64;
#pragma unroll
  for (int ci = 0; ci < 4; ci++) {
    const int col = n0 + wcol + ci * 16 + r16;
    const float bias = bp[col];
#pragma unroll
    for (int ri = 0; ri < 4; ri++)
#pragma unroll
      for (int r = 0; r < 4; r++) {
        const int m = m0 + wrow + ri * 16 + q * 4 + r;
        out[(size_t)m * EE + col] = acc[ri][ci][r] + bias;
      }
  }
}

// ---------------- flash attention (round 5) ----------------
// Wave (qh=w&1, kh=w>>1) computes 64 q-rows x its 32-key half of each tile:
// halves the per-wave K/V fragment reads (8 ds_read_b128/iter vs 16) -- the
// LDS pipe was the binding resource at round 4. Partial O's (key-halves)
// combined once at the end via an LDS exchange in native C-fragment order.
// Row sums by per-lane VALU accumulation (MFMA pipe is now the bottleneck).
// vperm/Vt layout unchanged: kh maps to stored-key bit5 = base offset.
__global__ __launch_bounds__(256, 3) void attn_kernel(const u16* __restrict__ Qg, const u16* __restrict__ Kg,
                                                      const u16* __restrict__ Vg, u16* __restrict__ Ob) {
  __shared__ __align__(16) u16 Kd[2][4096];  // [buf][ks2][key64][32]
  __shared__ __align__(16) u16 Vd[2][4096];  // [buf][ks2][d64][32] (key-slots permuted)
  __shared__ float lws[256];                 // per-wave row-sum exchange
  const int tid = threadIdx.x, lane = tid & 63, wave = tid >> 6;
  const int q = lane >> 4, r16 = lane & 15;
  const int qh = wave & 1, kh = wave >> 1;
  // XCD swizzle: id%8 presumed XCD; give each bh a fixed XCD
  const int id = blockIdx.x + 16 * blockIdx.y;
  const int g = id & 7, s = id >> 3;
  const int bh = g * 8 + (s >> 4);
  const int q0 = (s & 15) * 128;
  const u16* Qp = Qg + ((size_t)bh * NN + q0) * DD;
  const u16* Kp = Kg + (size_t)bh * NN * DD;
  const u16* Vp = Vg + (size_t)bh * DD * NN;

  // Q fragments straight from global (B-operand layout: row=r16, k=q*8+j)
  // wave's q-rows: qh*64 + nj*16 + r16, nj in [0,4)
  short8 qf[4][2];  // [nj][ks]
#pragma unroll
  for (int nj = 0; nj < 4; nj++)
#pragma unroll
    for (int ks = 0; ks < 2; ks++)
      qf[nj][ks] = *(const short8*)(Qp + (qh * 64 + nj * 16 + r16) * 64 + ks * 32 + q * 8);

  // stage K/V tile 0 into buf 0
#pragma unroll
  for (int i = 0; i < 2; i++) {
    int c = i * 256 + tid;
    int ks = c >> 8, rem = c & 255, row = rem >> 2, k8 = rem & 3;
    async16(Kp + row * 64 + ks * 32 + k8 * 8, &Kd[0][c * 8]);
  }
#pragma unroll
  for (int i = 0; i < 2; i++) {
    int c = i * 256 + tid;
    int ks = c >> 8, rem = c & 255, d = rem >> 2, k8 = rem & 3;
    async16(Vp + d * NN + ks * 32 + k8 * 8, &Vd[0][c * 8]);
  }
  __syncthreads();  // tile0 landed

  f32x4 o[4][4];    // partial O [nj][ci]: rows qh*64+nj*16+q*4+r, cols ci*16+r16
  float lsum[4];    // per-lane partial row sums
#pragma unroll
  for (int i = 0; i < 4; i++) {
    lsum[i] = 0.f;
#pragma unroll
    for (int j = 0; j < 4; j++) o[i][j] = (f32x4){0.f, 0.f, 0.f, 0.f};
  }

  for (int j = 0; j < 32; j++) {
    const int buf = j & 1;
    // prefetch tile j+1 into the other buffer (overlaps with compute below)
    if (j < 31) {
      const u16* Kt_ = Kp + (j + 1) * 64 * 64;
#pragma unroll
      for (int i = 0; i < 2; i++) {
        int c = i * 256 + tid;
        int ks = c >> 8, rem = c & 255, row = rem >> 2, k8 = rem & 3;
        async16(Kt_ + row * 64 + ks * 32 + k8 * 8, &Kd[buf ^ 1][c * 8]);
      }
#pragma unroll
      for (int i = 0; i < 2; i++) {
        int c = i * 256 + tid;
        int ks = c >> 8, rem = c & 255, d = rem >> 2, k8 = rem & 3;
        async16(Vp + d * NN + (j + 1) * 64 + ks * 32 + k8 * 8, &Vd[buf ^ 1][c * 8]);
      }
    }

    // S^T = K.Q^T over this wave's 32 keys: st[mi][nj]; keys kh*32+mi*16+q*4+r
    f32x4 st[2][4];
#pragma unroll
    for (int mi = 0; mi < 2; mi++)
#pragma unroll
      for (int nj = 0; nj < 4; nj++) st[mi][nj] = (f32x4){0.f, 0.f, 0.f, 0.f};
#pragma unroll
    for (int ks = 0; ks < 2; ks++) {
      short8 kf[2];
#pragma unroll
      for (int mi = 0; mi < 2; mi++)
        kf[mi] = *(const short8*)&Kd[buf][ks * 2048 + (kh * 32 + mi * 16 + r16) * 32 + q * 8];
#pragma unroll
      for (int mi = 0; mi < 2; mi++)
#pragma unroll
        for (int nj = 0; nj < 4; nj++)
          st[mi][nj] = __builtin_amdgcn_mfma_f32_16x16x32_bf16(kf[mi], qf[nj][ks], st[mi][nj], 0, 0, 0);
    }

    // p = exp2(s'); accumulate row sums per-lane; pack in-register
    uint2 pka[2][4];  // [mi][nj]
#pragma unroll
    for (int mi = 0; mi < 2; mi++)
#pragma unroll
      for (int nj = 0; nj < 4; nj++) {
        float p0 = EXP2(st[mi][nj][0]);
        float p1 = EXP2(st[mi][nj][1]);
        float p2 = EXP2(st[mi][nj][2]);
        float p3 = EXP2(st[mi][nj][3]);
        lsum[nj] += (p0 + p1) + (p2 + p3);
        pka[mi][nj].x = pk2(p0, p1);
        pka[mi][nj].y = pk2(p2, p3);
      }

    // O += P.V over the wave's 32 keys (stored V cols kh*32 + q*8 + j)
    short8 vf[4];
#pragma unroll
    for (int ci = 0; ci < 4; ci++)
      vf[ci] = *(const short8*)&Vd[buf][kh * 2048 + (ci * 16 + r16) * 32 + q * 8];
#pragma unroll
    for (int nj = 0; nj < 4; nj++) {
      union { uint4 u; short8 s; } a;
      a.u.x = pka[0][nj].x;
      a.u.y = pka[0][nj].y;
      a.u.z = pka[1][nj].x;
      a.u.w = pka[1][nj].y;
#pragma unroll
      for (int ci = 0; ci < 4; ci++)
        o[nj][ci] = __builtin_amdgcn_mfma_f32_16x16x32_bf16(a.s, vf[ci], o[nj][ci], 0, 0, 0);
    }

    __syncthreads();  // drains prefetch (issued a full compute phase ago); buffer handoff
  }

  // --- combine key-halves ---
  // quad-reduce row sums (lanes with same r16: xor 16, 32), publish per wave
#pragma unroll
  for (int nj = 0; nj < 4; nj++) {
    lsum[nj] += __shfl_xor(lsum[nj], 16);
    lsum[nj] += __shfl_xor(lsum[nj], 32);
  }
  if (lane < 16) {
#pragma unroll
    for (int nj = 0; nj < 4; nj++) lws[wave * 64 + nj * 16 + lane] = lsum[nj];
  }
  // kh=1 waves dump partial O in native C-fragment order (b128, conflict-free)
  float* Oex = (qh == 0) ? (float*)Kd : (float*)Vd;  // 16KB each, free after loop
  if (kh == 1) {
#pragma unroll
    for (int nj = 0; nj < 4; nj++)
#pragma unroll
      for (int ci = 0; ci < 4; ci++)
        *(f32x4*)&Oex[((nj * 4 + ci) * 64 + lane) * 4] = o[nj][ci];
  }
  __syncthreads();
  if (kh == 0) {
    const int b = bh >> 4, h = bh & 15;
#pragma unroll
    for (int nj = 0; nj < 4; nj++) {
#pragma unroll
      for (int ci = 0; ci < 4; ci++) {
        f32x4 p = *(const f32x4*)&Oex[((nj * 4 + ci) * 64 + lane) * 4];
        o[nj][ci] += p;
      }
      // total row sums for rows nj*16 + q*4 + r
      float linv[4];
#pragma unroll
      for (int r = 0; r < 4; r++) {
        const int i = nj * 16 + q * 4 + r;
        linv[r] = 1.0f / (lws[wave * 64 + i] + lws[(wave + 2) * 64 + i]);
      }
#pragma unroll
      for (int r = 0; r < 4; r++) {
        const int n = q0 + qh * 64 + nj * 16 + q * 4 + r;
#pragma unroll
        for (int ci = 0; ci < 4; ci++) {
          const int d = ci * 16 + r16;
          Ob[((size_t)(b * NN + n)) * EE + h * 64 + d] = f2bf(o[nj][ci][r] * linv[r]);
        }
      }
    }
  }
}

// ---------------- launch ----------------

extern "C" void kernel_launch(void* const* d_in, const int* in_sizes, int n_in,
                              void* d_out, int out_size, void* d_ws, size_t ws_size,
                              hipStream_t stream) {
  const float* x     = (const float*)d_in[0];
  const float* Wqkv  = (const float*)d_in[1];
  const float* bqkv  = (const float*)d_in[2];
  const float* Wproj = (const float*)d_in[3];
  const float* bproj = (const float*)d_in[4];
  float* out = (float*)d_out;
  char* ws = (char*)d_ws;

  u16* Xb     = (u16*)(ws);                      // 16MB (aliased by Ob after gemm_qkv)
  u16* Ob     = Xb;
  u16* Qb     = (u16*)(ws + (size_t)(16 << 20)); // 16MB (pre-scaled by CS)
  u16* Kb     = (u16*)(ws + (size_t)(32 << 20)); // 16MB
  u16* Vt     = (u16*)(ws + (size_t)(48 << 20)); // 16MB  [bh][d][n-permuted]
  u16* WqkvT  = (u16*)(ws + (size_t)(64 << 20)); // 6MB   [c'][k]
  u16* WprojT = (u16*)(ws + (size_t)(72 << 20)); // 2MB   [e_out][e_in]

  prep_kernel<<<12288, 256, 0, stream>>>(x, Xb, Wqkv, WqkvT, Wproj, WprojT);
  gemm_qkv<<<dim3(24, 64), 256, 0, stream>>>(Xb, WqkvT, bqkv, Qb, Kb, Vt);
  attn_kernel<<<dim3(16, 64), 256, 0, stream>>>(Qb, Kb, Vt, Ob);
  gemm_proj<<<dim3(8, 64), 256, 0, stream>>>(Ob, WprojT, bproj, out);
}

// Round 6
// 271.681 us; speedup vs baseline: 1.0413x; 1.0413x over previous
//
#include <hip/hip_runtime.h>
#include <stdint.h>

typedef unsigned short u16;
typedef __attribute__((ext_vector_type(8))) short short8;   // 8 bf16 = 4 VGPRs
typedef __attribute__((ext_vector_type(4))) float f32x4;

#define LOG2E 1.44269504088896340736f
#define CS (0.03125f * LOG2E)   // softmax scale 1/sqrt(E)=1/32, folded into exp2 domain
// Problem dims
#define BB 4
#define NN 2048
#define EE 1024
#define HH 16
#define DD 64
#define MM 8192   // B*N
#define C3 3072   // 3*E

#if __has_builtin(__builtin_amdgcn_exp2f)
#define EXP2(x) __builtin_amdgcn_exp2f(x)
#else
#define EXP2(x) exp2f(x)
#endif

__device__ __forceinline__ u16 f2bf(float f) {
  union { float f; unsigned u; } v; v.f = f;
  unsigned r = v.u + 0x7fffu + ((v.u >> 16) & 1u);
  return (u16)(r >> 16);
}

// pack two floats to a bf16 pair; gfx950 has a HW packed convert
#if __has_builtin(__builtin_amdgcn_cvt_pk_bf16_f32)
typedef __attribute__((ext_vector_type(2))) __bf16 bf16x2;
__device__ __forceinline__ unsigned pk2(float a, float b) {
  union { bf16x2 v; unsigned u; } c;
  c.v = __builtin_amdgcn_cvt_pk_bf16_f32(a, b);
  return c.u;
}
#else
__device__ __forceinline__ unsigned pk2(float a, float b) {
  union { float f; unsigned u; } x, y; x.f = a; y.f = b;
  return ((x.u + 0x8000u) >> 16) | ((y.u + 0x8000u) & 0xffff0000u);
}
#endif

__device__ __forceinline__ void async16(const void* g, void* l) {
  __builtin_amdgcn_global_load_lds((const __attribute__((address_space(1))) void*)g,
                                   (__attribute__((address_space(3))) void*)l,
                                   16, 0, 0);
}

// in-tile V key permutation (matches in-register P fragment assembly):
// stored slot s from true key t (6 bits): s = (t5, t3, t2, t4, t1, t0)
__device__ __forceinline__ int vperm(int t) {
  return (t & 0x23) | ((t & 8) << 1) | ((t & 4) << 1) | ((t & 16) >> 2);
}

// ---------------- fused prep kernel ----------------
// blocks [0,8192): cast x fp32->bf16
// blocks [8192,11264): transpose+cast+permute Wqkv -> WqkvT[cp][k]
// blocks [11264,12288): transpose+cast Wproj -> WprojT[c][k]
__global__ __launch_bounds__(256) void prep_kernel(const float* __restrict__ x, u16* __restrict__ xb,
                                                   const float* __restrict__ Wqkv, u16* __restrict__ WqkvT,
                                                   const float* __restrict__ Wproj, u16* __restrict__ WprojT) {
  __shared__ float tile[32][33];
  const int bid = blockIdx.x;
  if (bid < 8192) {
    int i = (bid * 256 + threadIdx.x) * 4;
    float4 v = *(const float4*)(x + i);
    ushort4 o; o.x = f2bf(v.x); o.y = f2bf(v.y); o.z = f2bf(v.z); o.w = f2bf(v.w);
    *(ushort4*)(xb + i) = o;
    return;
  }
  const int permute = bid < 11264 ? 1 : 0;
  const float* W = permute ? Wqkv : Wproj;
  u16* Wt = permute ? WqkvT : WprojT;
  const int ncols = permute ? C3 : EE;
  const int t = permute ? bid - 8192 : bid - 11264;
  const int nbx = permute ? 96 : 32;
  const int c0 = (t % nbx) * 32, k0 = (t / nbx) * 32;
  const int tx = threadIdx.x & 31, ty = threadIdx.x >> 5;  // ty 0..7
#pragma unroll
  for (int r = 0; r < 32; r += 8)
    tile[ty + r][tx] = W[(size_t)(k0 + ty + r) * ncols + c0 + tx];
  __syncthreads();
#pragma unroll
  for (int r = 0; r < 32; r += 8) {
    int c = c0 + ty + r;
    int cp = c;
    if (permute) {
      int tt = c % 3, hh = c / 192, d = (c / 3) % 64;
      cp = tt * 1024 + hh * 64 + d;
    }
    Wt[(size_t)cp * EE + k0 + tx] = f2bf(tile[tx][ty + r]);
  }
}

// ---------------- GEMM core (BK=64, A[M,K] @ Bt[N,K]) ----------------
// LDS tiles stored as [ks2][row128][32] sub-tiles: keeps the conflict-free
// 64B row stride (a flat 128-u16 row stride would be an exact 32-bank alias
// -> 16-way conflict). BK=64 halves barrier count vs m97's BK=32 and doubles
// MFMA-per-barrier to 32 -- attacks the vmcnt(0) barrier-drain stall.
template <int KDIM>
__device__ __forceinline__ void gemm_core(const u16* __restrict__ A, const u16* __restrict__ Bt,
                                          int m0, int n0, u16* As, u16* Bs, f32x4 acc[4][4]) {
  const int tid = threadIdx.x;
  const int lane = tid & 63, wave = tid >> 6;
  const int q = lane >> 4, r16 = lane & 15;
  const int wrow = (wave >> 1) * 64, wcol = (wave & 1) * 64;
#pragma unroll
  for (int i = 0; i < 4; i++)
#pragma unroll
    for (int j = 0; j < 4; j++) acc[i][j] = (f32x4){0.f, 0.f, 0.f, 0.f};

  for (int k0 = 0; k0 < KDIM; k0 += 64) {
#pragma unroll
    for (int i = 0; i < 4; i++) {
      int c = i * 256 + tid;  // 0..1023: ks = c>>9, row = (c&511)>>2, k8 = c&3
      int ks = c >> 9, rem = c & 511, row = rem >> 2, k8 = rem & 3;
      async16(A + (size_t)(m0 + row) * KDIM + k0 + ks * 32 + k8 * 8, &As[c * 8]);
    }
#pragma unroll
    for (int i = 0; i < 4; i++) {
      int c = i * 256 + tid;
      int ks = c >> 9, rem = c & 511, row = rem >> 2, k8 = rem & 3;
      async16(Bt + (size_t)(n0 + row) * KDIM + k0 + ks * 32 + k8 * 8, &Bs[c * 8]);
    }
    __syncthreads();
#pragma unroll
    for (int ks = 0; ks < 2; ks++) {
      short8 af[4], bf[4];
#pragma unroll
      for (int i = 0; i < 4; i++)
        af[i] = *(const short8*)&As[ks * 4096 + (wrow + i * 16 + r16) * 32 + q * 8];
#pragma unroll
      for (int i = 0; i < 4; i++)
        bf[i] = *(const short8*)&Bs[ks * 4096 + (wcol + i * 16 + r16) * 32 + q * 8];
#pragma unroll
      for (int i = 0; i < 4; i++)
#pragma unroll
        for (int j = 0; j < 4; j++)
          acc[i][j] = __builtin_amdgcn_mfma_f32_16x16x32_bf16(af[i], bf[j], acc[i][j], 0, 0, 0);
    }
    __syncthreads();
  }
}

// QKV GEMM: X[8192,1024] @ WqkvT -> Q(pre-scaled by CS),K to [bh][n][d], V to [bh][d][vperm(n)]
__global__ __launch_bounds__(256) void gemm_qkv(const u16* __restrict__ Xb, const u16* __restrict__ Wt,
                                                const float* __restrict__ bqkv, u16* __restrict__ Qb,
                                                u16* __restrict__ Kb, u16* __restrict__ Vt) {
  __shared__ __align__(16) u16 As[128 * 64];
  __shared__ __align__(16) u16 Bs[128 * 64];
  f32x4 acc[4][4];
  const int m0 = blockIdx.y * 128, n0 = blockIdx.x * 128;
  gemm_core<EE>(Xb, Wt, m0, n0, As, Bs, acc);
  const int tid = threadIdx.x, lane = tid & 63, wave = tid >> 6;
  const int q = lane >> 4, r16 = lane & 15;
  const int wrow = (wave >> 1) * 64, wcol = (wave & 1) * 64;
  // each 128-col block lies entirely in one t-region (Q, K, or V)
  const int t = (n0 + wcol) >> 10;
  const int b = (m0 + wrow) >> 11;          // wave-uniform batch
#pragma unroll
  for (int ci = 0; ci < 4; ci++) {
    const int cp = n0 + wcol + ci * 16 + r16;  // permuted col: t*1024 + h*64 + d
    const int hh = (cp >> 6) & 15, d = cp & 63;
    const float bias = bqkv[hh * 192 + d * 3 + t];  // bias permute folded in
    if (t == 0) {
#pragma unroll
      for (int ri = 0; ri < 4; ri++)
#pragma unroll
        for (int r = 0; r < 4; r++) {
          const int m = m0 + wrow + ri * 16 + q * 4 + r;
          Qb[((size_t)(b * 16 + hh) * 2048 + (m & 2047)) * 64 + d] = f2bf((acc[ri][ci][r] + bias) * CS);
        }
    } else if (t == 1) {
#pragma unroll
      for (int ri = 0; ri < 4; ri++)
#pragma unroll
        for (int r = 0; r < 4; r++) {
          const int m = m0 + wrow + ri * 16 + q * 4 + r;
          Kb[((size_t)(b * 16 + hh) * 2048 + (m & 2047)) * 64 + d] = f2bf(acc[ri][ci][r] + bias);
        }
    } else {
      // V: C rows (quad*4+reg) are n-consecutive; store 8B at the in-tile permuted slot
#pragma unroll
      for (int ri = 0; ri < 4; ri++) {
        const int nb = (m0 + wrow + ri * 16 + q * 4) & 2047;
        const int ns = (nb & ~63) + vperm(nb & 63);  // 4-aligned -> 4-contiguous preserved
        ushort4 w;
        w.x = f2bf(acc[ri][ci][0] + bias);
        w.y = f2bf(acc[ri][ci][1] + bias);
        w.z = f2bf(acc[ri][ci][2] + bias);
        w.w = f2bf(acc[ri][ci][3] + bias);
        *(ushort4*)&Vt[((size_t)(b * 16 + hh) * 64 + d) * 2048 + ns] = w;
      }
    }
  }
}

// Proj GEMM: O[8192,1024] @ WprojT + bproj -> fp32 out
__global__ __launch_bounds__(256) void gemm_proj(const u16* __restrict__ Ob, const u16* __restrict__ Wt,
                                                 const float* __restrict__ bp, float* __restrict__ out) {
  __shared__ __align__(16) u16 As[128 * 64];
  __shared__ __align__(16) u16 Bs[128 * 64];
  f32x4 acc[4][4];
  const int m0 = blockIdx.y * 128, n0 = blockIdx.x * 128;
  gemm_core<EE>(Ob, Wt, m0, n0, As, Bs, acc);
  const int tid = threadIdx.x, lane = tid & 63, wave = tid >> 6;
  const int q = lane >> 4, r16 = lane & 15;
  const int wrow = (wave >> 1) * 64, wcol = (wave & 1) * 64;
#pragma unroll
  for (int ci = 0; ci < 4; ci++) {
    const int col = n0 + wcol + ci * 16 + r16;
    const float bias = bp[col];
#pragma unroll
    for (int ri = 0; ri < 4; ri++)
#pragma unroll
      for (int r = 0; r < 4; r++) {
        const int m = m0 + wrow + ri * 16 + q * 4 + r;
        out[(size_t)m * EE + col] = acc[ri][ci][r] + bias;
      }
  }
}

// ---------------- flash attention (round 4 structure, reverted from R5) ----------------
// P never touches LDS: the PV contraction is key-permutation invariant, so the
// A-fragment is assembled IN-REGISTER from each lane's own packed exp2 outputs
// (slot->key map tau(q,kp,j) = (2kp+(j>>2))*16+4q+(j&3)); V is stored globally
// with the matching in-tile permutation by gemm_qkv. LDS = Kd+Vd = 32KB -> 4 blocks/CU.
// R5's key-split-across-waves regressed (latency-bound, not LDS-pipe-bound) -- keep R4.
__global__ __launch_bounds__(256, 4) void attn_kernel(const u16* __restrict__ Qg, const u16* __restrict__ Kg,
                                                      const u16* __restrict__ Vg, u16* __restrict__ Ob) {
  __shared__ __align__(16) u16 Kd[2][4096];  // [buf][ks2][key64][32]
  __shared__ __align__(16) u16 Vd[2][4096];  // [buf][ks2][d64][32] (key-slots permuted)
  const int tid = threadIdx.x, lane = tid & 63, wave = tid >> 6;
  const int q = lane >> 4, r16 = lane & 15;
  // XCD swizzle: id%8 presumed XCD; give each bh a fixed XCD
  const int id = blockIdx.x + 16 * blockIdx.y;
  const int g = id & 7, s = id >> 3;
  const int bh = g * 8 + (s >> 4);
  const int q0 = (s & 15) * 128;
  const u16* Qp = Qg + ((size_t)bh * NN + q0) * DD;
  const u16* Kp = Kg + (size_t)bh * NN * DD;
  const u16* Vp = Vg + (size_t)bh * DD * NN;

  // Q fragments straight from global (B-operand layout: row=r16, k=q*8+j)
  short8 qf[2][2];  // [nj][ks]
#pragma unroll
  for (int nj = 0; nj < 2; nj++)
#pragma unroll
    for (int ks = 0; ks < 2; ks++)
      qf[nj][ks] = *(const short8*)(Qp + (wave * 32 + nj * 16 + r16) * 64 + ks * 32 + q * 8);

  // stage K/V tile 0 into buf 0
#pragma unroll
  for (int i = 0; i < 2; i++) {
    int c = i * 256 + tid;
    int ks = c >> 8, rem = c & 255, row = rem >> 2, k8 = rem & 3;
    async16(Kp + row * 64 + ks * 32 + k8 * 8, &Kd[0][c * 8]);
  }
#pragma unroll
  for (int i = 0; i < 2; i++) {
    int c = i * 256 + tid;
    int ks = c >> 8, rem = c & 255, d = rem >> 2, k8 = rem & 3;
    async16(Vp + d * NN + ks * 32 + k8 * 8, &Vd[0][c * 8]);
  }
  __syncthreads();  // tile0 landed

  f32x4 o[2][4];    // O accumulator [ri][ci]
  f32x4 ol[2];      // row-sum accumulator via ones-MFMA
#pragma unroll
  for (int i = 0; i < 2; i++) {
    ol[i] = (f32x4){0.f, 0.f, 0.f, 0.f};
#pragma unroll
    for (int j = 0; j < 4; j++) o[i][j] = (f32x4){0.f, 0.f, 0.f, 0.f};
  }
  const short8 ones = {16256, 16256, 16256, 16256, 16256, 16256, 16256, 16256};  // bf16 1.0

  for (int j = 0; j < 32; j++) {
    const int buf = j & 1;
    // prefetch tile j+1 into the other buffer (overlaps with compute below)
    if (j < 31) {
      const u16* Kt_ = Kp + (j + 1) * 64 * 64;
#pragma unroll
      for (int i = 0; i < 2; i++) {
        int c = i * 256 + tid;
        int ks = c >> 8, rem = c & 255, row = rem >> 2, k8 = rem & 3;
        async16(Kt_ + row * 64 + ks * 32 + k8 * 8, &Kd[buf ^ 1][c * 8]);
      }
#pragma unroll
      for (int i = 0; i < 2; i++) {
        int c = i * 256 + tid;
        int ks = c >> 8, rem = c & 255, d = rem >> 2, k8 = rem & 3;
        async16(Vp + d * NN + (j + 1) * 64 + ks * 32 + k8 * 8, &Vd[buf ^ 1][c * 8]);
      }
    }

    // S^T = K.Q^T : st[mi][nj]; m = keys, n = q-rows (already in exp2 domain)
    f32x4 st[4][2];
#pragma unroll
    for (int mi = 0; mi < 4; mi++)
#pragma unroll
      for (int nj = 0; nj < 2; nj++) st[mi][nj] = (f32x4){0.f, 0.f, 0.f, 0.f};
#pragma unroll
    for (int ks = 0; ks < 2; ks++) {
      short8 kf[4];
#pragma unroll
      for (int mi = 0; mi < 4; mi++)
        kf[mi] = *(const short8*)&Kd[buf][ks * 2048 + (mi * 16 + r16) * 32 + q * 8];
#pragma unroll
      for (int mi = 0; mi < 4; mi++)
#pragma unroll
        for (int nj = 0; nj < 2; nj++)
          st[mi][nj] = __builtin_amdgcn_mfma_f32_16x16x32_bf16(kf[mi], qf[nj][ks], st[mi][nj], 0, 0, 0);
    }

    // p = exp2(s'); pack in-register (keys stay lane-local; no LDS round-trip)
    uint2 pka[4][2];  // [mi][nj] = (pk(r0,r1), pk(r2,r3))
#pragma unroll
    for (int mi = 0; mi < 4; mi++)
#pragma unroll
      for (int nj = 0; nj < 2; nj++) {
        float p0 = EXP2(st[mi][nj][0]);
        float p1 = EXP2(st[mi][nj][1]);
        float p2 = EXP2(st[mi][nj][2]);
        float p3 = EXP2(st[mi][nj][3]);
        pka[mi][nj].x = pk2(p0, p1);
        pka[mi][nj].y = pk2(p2, p3);
      }

    // O += P.V ; row-sums += P.1  (A-frags assembled in-register)
#pragma unroll
    for (int kp = 0; kp < 2; kp++) {
      short8 vf[4];
#pragma unroll
      for (int ci = 0; ci < 4; ci++)
        vf[ci] = *(const short8*)&Vd[buf][kp * 2048 + (ci * 16 + r16) * 32 + q * 8];
#pragma unroll
      for (int ri = 0; ri < 2; ri++) {
        union { uint4 u; short8 s; } a;
        a.u.x = pka[2 * kp][ri].x;
        a.u.y = pka[2 * kp][ri].y;
        a.u.z = pka[2 * kp + 1][ri].x;
        a.u.w = pka[2 * kp + 1][ri].y;
#pragma unroll
        for (int ci = 0; ci < 4; ci++)
          o[ri][ci] = __builtin_amdgcn_mfma_f32_16x16x32_bf16(a.s, vf[ci], o[ri][ci], 0, 0, 0);
        ol[ri] = __builtin_amdgcn_mfma_f32_16x16x32_bf16(a.s, ones, ol[ri], 0, 0, 0);
      }
    }

    __syncthreads();  // drains prefetch (issued a full compute phase ago); buffer handoff
  }

  // epilogue: O/l -> Ob[b][n][h*64+d] bf16; no reduction needed (ones-trick)
  const int b = bh >> 4, h = bh & 15;
#pragma unroll
  for (int ri = 0; ri < 2; ri++)
#pragma unroll
    for (int r = 0; r < 4; r++) {
      const float inv = 1.0f / ol[ri][r];
      const int n = q0 + wave * 32 + ri * 16 + q * 4 + r;
#pragma unroll
      for (int ci = 0; ci < 4; ci++) {
        const int d = ci * 16 + r16;
        Ob[((size_t)(b * NN + n)) * EE + h * 64 + d] = f2bf(o[ri][ci][r] * inv);
      }
    }
}

// ---------------- launch ----------------

extern "C" void kernel_launch(void* const* d_in, const int* in_sizes, int n_in,
                              void* d_out, int out_size, void* d_ws, size_t ws_size,
                              hipStream_t stream) {
  const float* x     = (const float*)d_in[0];
  const float* Wqkv  = (const float*)d_in[1];
  const float* bqkv  = (const float*)d_in[2];
  const float* Wproj = (const float*)d_in[3];
  const float* bproj = (const float*)d_in[4];
  float* out = (float*)d_out;
  char* ws = (char*)d_ws;

  u16* Xb     = (u16*)(ws);                      // 16MB (aliased by Ob after gemm_qkv)
  u16* Ob     = Xb;
  u16* Qb     = (u16*)(ws + (size_t)(16 << 20)); // 16MB (pre-scaled by CS)
  u16* Kb     = (u16*)(ws + (size_t)(32 << 20)); // 16MB
  u16* Vt     = (u16*)(ws + (size_t)(48 << 20)); // 16MB  [bh][d][n-permuted]
  u16* WqkvT  = (u16*)(ws + (size_t)(64 << 20)); // 6MB   [c'][k]
  u16* WprojT = (u16*)(ws + (size_t)(72 << 20)); // 2MB   [e_out][e_in]

  prep_kernel<<<12288, 256, 0, stream>>>(x, Xb, Wqkv, WqkvT, Wproj, WprojT);
  gemm_qkv<<<dim3(24, 64), 256, 0, stream>>>(Xb, WqkvT, bqkv, Qb, Kb, Vt);
  attn_kernel<<<dim3(16, 64), 256, 0, stream>>>(Qb, Kb, Vt, Ob);
  gemm_proj<<<dim3(8, 64), 256, 0, stream>>>(Ob, WprojT, bproj, out);
}